// Round 16
// baseline (65.986 us; speedup 1.0000x reference)
//
#include <hip/hip_runtime.h>
#include <math.h>

// Dual-branch shifted-window self-attention — FUSED single kernel.
// Blocks 0..1023:  branch 1 (16x16 windows, shift (8,8), ch 32..63 -> out 16..31),
//                  MFMA body + V pre-permuted LDS layout (round-11 verified,
//                  1-wide m-loop — round 15 proved 2-wide ILP regresses).
// Blocks 1024..3071: branch 0 (8x8 windows, no shift, ch 0..31 -> out 0..15),
//                  fp32 vector body verbatim (round-9 verified), 8 independent
//                  waves per block (wave-private LDS slices, no barrier).
//
// Round-16 change (single, isolated, semantically inert): the win16 compute
// phase is bracketed with s_setprio(1)/(0). Mechanism (T5, m191): win16 and
// win8 blocks are co-resident, independent, and at different phases on each
// SIMD; elevating the MFMA+exp critical path makes the win8 pure-VALU waves a
// strict stall-filler instead of round-robin competitors.
//
// Numerics (verified rounds 4/6/9/11): q pre-scaled by sqrt(1/ln2) so e^S =
// exp2(q'.q'^T) — bare v_exp_f32, no max subtraction. P = bf16_rne(exp2),
// used for BOTH numerator and ones-column row-sum l (self-normalizing).
// Q Dekker hi/lo; V bf16-RNE. Unnormalized P is symmetric: QK C-fragment of
// tile (s,t) IS the PV A-fragment of tile (t,s) under the shared K-slot
// placement lambda(g,j) = 16*(j>=4) + 4g + (j&3); V stored in LDS pre-permuted
// to lambda order with channel-row 4 = ones (V B-fragment = ONE ds_read_b128).
// cvt_pk stays INLINE ASM (round 12: the intrinsic lowers to software RNE).

typedef __attribute__((ext_vector_type(4))) float f32x4;
typedef __attribute__((ext_vector_type(8))) short short8;

static constexpr int Ww = 256;
static constexpr int CIN = 64;
static constexpr int COUT = 32;
static constexpr size_t PLANE = 65536; // 256*256
static constexpr float ALPHA = 1.2011224087864498f; // sqrt(1/ln2)

__device__ inline float fexp2(float x) {
#if __has_builtin(__builtin_amdgcn_exp2f)
    return __builtin_amdgcn_exp2f(x);
#else
    float r;
    asm("v_exp_f32 %0, %1" : "=v"(r) : "v"(x));   // v_exp_f32 IS 2^x
    return r;
#endif
}

// pack two f32 -> one u32 of 2x bf16 (RNE), single instruction on gfx950
__device__ inline unsigned cvt_pk_bf16(float lo, float hi) {
    unsigned r;
    asm("v_cvt_pk_bf16_f32 %0, %1, %2" : "=v"(r) : "v"(lo), "v"(hi));
    return r;
}

__device__ inline unsigned short bfhi_u(float x) {   // truncation (Dekker hi)
    union { float f; unsigned u; } u; u.f = x;
    return (unsigned short)(u.u >> 16);
}
__device__ inline float bf2f(unsigned short h) {
    union { unsigned u; float f; } u; u.u = ((unsigned)h) << 16;
    return u.f;
}
__device__ inline unsigned short bf_rne(float x) {   // round-nearest-even bf16
    union { float f; unsigned u; } u; u.f = x;
    return (unsigned short)((u.u + 0x7FFFu + ((u.u >> 16) & 1u)) >> 16);
}

struct Smem16 {                                   // 31360 B (win16 path)
    unsigned short qpack[4][256][8];              // 16384
    unsigned short vperm[4][5][272];              // 10880 (row 544 B, 16B-aligned)
    float l_lds[4][256];                          // 4096
};
struct Smem8 {                                    // 16384 B (win8 path)
    float4 qs[8][64];
    float4 vs[8][64];
};
union SmemU { Smem16 a; Smem8 b; };

__global__ __launch_bounds__(512) void fused_attn(const float* __restrict__ x,
                                                  float* __restrict__ out) {
    __shared__ __align__(16) SmemU smem;

    const int tid  = threadIdx.x;
    const int lane = tid & 63;
    const int wave = tid >> 6;

    if (blockIdx.x < 1024) {
        // ================= branch 1: 16x16, shift (8,8), MFMA ================
        const int blk = blockIdx.x;
        const int wj = blk & 15, wi = (blk >> 4) & 15, b = blk >> 8;
        const int head = wave >> 1;
        const int half = wave & 1;
        const int g = lane >> 4;
        const int n = lane & 15;

        // ---- global -> LDS; q * ALPHA then Dekker split; v bf16-RNE permuted.
#pragma unroll
        for (int k = 0; k < 16; ++k) {
            const int f = k * 512 + tid;
            const int c = f >> 8;            // 0..31
            const int t = f & 255;
            const int gi = (wi * 16 + (t >> 4) + 248) & 255;   // src = rolled-8 mod 256
            const int gj = (wj * 16 + (t & 15) + 248) & 255;
            float val = x[((size_t)b * CIN + 32 + c) * PLANE + (size_t)gi * Ww + gj];
            const int h = (c >> 2) & 3, ch = c & 3;
            if (c < 16) {
                val *= ALPHA;
                const unsigned short hi = bfhi_u(val);
                smem.a.qpack[h][t][ch]     = hi;
                smem.a.qpack[h][t][4 + ch] = bfhi_u(val - bf2f(hi));
            } else {
                // source s-offset rr = hi*16 + 4g + j  ->  pos = g*8 + hi*4 + j
                const int rr = t & 31;
                const int pos = (t & ~31) + ((rr >> 2) & 3) * 8 + (rr >> 4) * 4 + (rr & 3);
                smem.a.vperm[h][ch][pos] = bf_rne(val);
            }
        }
        // ones channel-row: read as K-slot data -> row sums l
#pragma unroll
        for (int k = 0; k < 2; ++k) {
            const int i = k * 512 + tid;
            smem.a.vperm[i >> 8][4][i & 255] = (unsigned short)0x3F80;
        }
        __syncthreads();

        // Elevate the win16 critical path over co-resident win8 backfill waves.
        __builtin_amdgcn_s_setprio(1);

        const int tbase = half * 128;

        const unsigned long long m0  = (g == 0) ? ~0ull : 0ull;
        const unsigned long long m1  = (g == 1) ? ~0ull : 0ull;
        const unsigned long long m01 = (g <  2) ? ~0ull : 0ull;

        // QK K-slot placement: A:[s_hi(g0) s_hi(g1) 0 0 | s_lo(g0) 0 0 0]
        //                      B:[t_hi(g0) t_lo(g1) 0 0 | t_hi(g0) 0 0 0]
        short8 BQ[8];
#pragma unroll
        for (int m = 0; m < 8; ++m) {
            union { short8 v; unsigned long long q[2]; } u, f;
            u.v = *(const short8*)&smem.a.qpack[head][tbase + m * 16 + n][0];
            f.q[0] = (u.q[0] & m0) | (u.q[1] & m1);
            f.q[1] = u.q[0] & m0;
            BQ[m] = f.v;
        }

        f32x4 O[8];
#pragma unroll
        for (int m = 0; m < 8; ++m) O[m] = (f32x4){0.f, 0.f, 0.f, 0.f};
        const f32x4 zero4 = (f32x4){0.f, 0.f, 0.f, 0.f};

        for (int c = 0; c < 8; ++c) {                 // s-chunks of 32
            short8 AQ[2];
#pragma unroll
            for (int a = 0; a < 2; ++a) {
                union { short8 v; unsigned long long q[2]; } u, f;
                u.v = *(const short8*)&smem.a.qpack[head][c * 32 + a * 16 + n][0];
                f.q[0] = u.q[0] & m01;
                f.q[1] = u.q[1] & m0;
                AQ[a] = f.v;
            }

            // V B-fragment: pre-permuted -> one 16B read (rows 0..3 data, 4 ones)
            short8 Vhf = {0, 0, 0, 0, 0, 0, 0, 0};
            if (n < 5) Vhf = *(const short8*)&smem.a.vperm[head][n][c * 32 + g * 8];

            // per m: QK (2 MFMA) -> exp2 -> cvt_pk -> PV (1 MFMA).
#pragma unroll
            for (int m = 0; m < 8; ++m) {
                const f32x4 c0 = __builtin_amdgcn_mfma_f32_16x16x32_bf16(AQ[0], BQ[m], zero4, 0, 0, 0);
                const f32x4 c1 = __builtin_amdgcn_mfma_f32_16x16x32_bf16(AQ[1], BQ[m], zero4, 0, 0, 0);
                union { unsigned u[4]; short8 s; } pk;
                pk.u[0] = cvt_pk_bf16(fexp2(c0[0]), fexp2(c0[1]));
                pk.u[1] = cvt_pk_bf16(fexp2(c0[2]), fexp2(c0[3]));
                pk.u[2] = cvt_pk_bf16(fexp2(c1[0]), fexp2(c1[1]));
                pk.u[3] = cvt_pk_bf16(fexp2(c1[2]), fexp2(c1[3]));
                O[m] = __builtin_amdgcn_mfma_f32_16x16x32_bf16(pk.s, Vhf, O[m], 0, 0, 0);
            }
        }

        __builtin_amdgcn_s_setprio(0);

        if (n == 4) {
#pragma unroll
            for (int m = 0; m < 8; ++m)
#pragma unroll
                for (int r = 0; r < 4; ++r)
                    smem.a.l_lds[head][tbase + m * 16 + 4 * g + r] = __builtin_amdgcn_rcpf(O[m][r]);
        }
        if (n < 4) {
            float* op = out + ((size_t)b * COUT + 16 + head * 4 + n) * PLANE;
#pragma unroll
            for (int m = 0; m < 8; ++m) {
                const f32x4 inv4 = *(const f32x4*)&smem.a.l_lds[head][tbase + m * 16 + 4 * g];
                const int gi  = (wi * 16 + half * 8 + m + 248) & 255;
                const int gj0 = (wj * 16 + 4 * g + 248) & 255;
                f32x4 res;
                res[0] = O[m][0] * inv4[0];
                res[1] = O[m][1] * inv4[1];
                res[2] = O[m][2] * inv4[2];
                res[3] = O[m][3] * inv4[3];
                *(f32x4*)(op + (size_t)gi * Ww + gj0) = res;
            }
        }
    } else {
        // ============ branch 0: 8x8, no shift, fp32 vector (round-9 verbatim) =
        int bid = (blockIdx.x - 1024) * 8 + wave;   // 0..16383
        const int wj   = bid & 31; bid >>= 5;
        const int wi   = bid & 31; bid >>= 5;
        const int head = bid & 3;  bid >>= 2;
        const int b    = bid;

        const int t  = lane;
        const int gi = wi * 8 + (t >> 3);
        const int gj = wj * 8 + (t & 7);
        const size_t pix = (size_t)gi * Ww + gj;

        const float* xq = x + (size_t)b * CIN * PLANE + (size_t)(head * 4) * PLANE + pix;
        const float* xv = xq + 16 * PLANE;

        float4* qs = smem.b.qs[wave];
        float4* vs = smem.b.vs[wave];

        float4 q, v;
        q.x = xq[0] * ALPHA; q.y = xq[PLANE] * ALPHA;
        q.z = xq[2 * PLANE] * ALPHA; q.w = xq[3 * PLANE] * ALPHA;
        v.x = xv[0];         v.y = xv[PLANE];     v.z = xv[2 * PLANE]; v.w = xv[3 * PLANE];
        qs[t] = q;
        vs[t] = v;
        // no barrier: qs/vs slices are wave-private; DS pipe is in-order per wave.

        float l = 0.f;
        float4 acc = make_float4(0.f, 0.f, 0.f, 0.f);
#pragma unroll
        for (int s = 0; s < 64; ++s) {
            const float4 p = qs[s];
            const float d = q.x * p.x + q.y * p.y + q.z * p.z + q.w * p.w;
            const float e = fexp2(d);
            l += e;
            const float4 vv = vs[s];
            acc.x += e * vv.x; acc.y += e * vv.y;
            acc.z += e * vv.z; acc.w += e * vv.w;
        }
        const float inv = 1.0f / l;

        float* ob = out + (size_t)b * COUT * PLANE + (size_t)(head * 4) * PLANE + pix;
        ob[0]         = acc.x * inv;
        ob[PLANE]     = acc.y * inv;
        ob[2 * PLANE] = acc.z * inv;
        ob[3 * PLANE] = acc.w * inv;
    }
}

extern "C" void kernel_launch(void* const* d_in, const int* in_sizes, int n_in,
                              void* d_out, int out_size, void* d_ws, size_t ws_size,
                              hipStream_t stream) {
    const float* x = (const float*)d_in[0];
    float* out = (float*)d_out;

    // blocks 0..1023: win16 (long pole, dispatched first);
    // blocks 1024..3071: win8 (16384 window-heads / 8 waves per block).
    hipLaunchKernelGGL(fused_attn, dim3(3072), dim3(512), 0, stream, x, out);
}

// Round 17
// 59.687 us; speedup vs baseline: 1.1055x; 1.1055x over previous
//
#include <hip/hip_runtime.h>
#include <math.h>

// Dual-branch shifted-window self-attention — FUSED single kernel.
// FINAL: round-9/11 anchor verbatim (59.5us, absmax 0.015625).
//
// Blocks 0..1023:  branch 1 (16x16 windows, shift (8,8), ch 32..63 -> out 16..31),
//                  MFMA body + V pre-permuted LDS layout.
// Blocks 1024..3071: branch 0 (8x8 windows, no shift, ch 0..31 -> out 0..15),
//                  fp32 vector body, 8 independent waves per block
//                  (wave-private LDS slices, no barrier needed).
// Block order: win16 first (long pole), win8 backfills its tail and stalls.
//
// Session findings baked in:
//  - exp2 pre-scale (q *= sqrt(1/ln2)) -> bare v_exp_f32, no max-subtraction
//    (scores bounded; 2^65 in f32 range). Verified rounds 4/6/9/11.
//  - P = bf16_rne(exp2(S)) feeds BOTH numerator and the ones-column row-sum l,
//    so bf16 weight error self-normalizes. V bf16-RNE; Q Dekker hi/lo split.
//  - Unnormalized P is symmetric: QK C-fragment of tile (s,t) IS the PV
//    A-fragment of tile (t,s) under shared K-slot placement
//    lambda(g,j) = 16*(j>=4) + 4g + (j&3) -> exp+cvt in-register, no cross-lane.
//  - V pre-permuted in LDS to lambda order, channel-row 4 = ones: V B-fragment
//    is ONE ds_read_b128 (neutral vs gathers, kept for fewer instructions).
//  - cvt_pk MUST be inline asm: __float22bfloat162_rn lowers to software RNE
//    (round 12: +23% dur). Measured dead ends: 2-wide m-ILP (-5%), setprio
//    (-11%), %3 block interleave + v_pk_f32 asm (-14%), win8-on-MFMA
//    (3x deterministic correctness failures; scratch-demoted when unified).

typedef __attribute__((ext_vector_type(4))) float f32x4;
typedef __attribute__((ext_vector_type(8))) short short8;

static constexpr int Ww = 256;
static constexpr int CIN = 64;
static constexpr int COUT = 32;
static constexpr size_t PLANE = 65536; // 256*256
static constexpr float ALPHA = 1.2011224087864498f; // sqrt(1/ln2)

__device__ inline float fexp2(float x) {
#if __has_builtin(__builtin_amdgcn_exp2f)
    return __builtin_amdgcn_exp2f(x);
#else
    float r;
    asm("v_exp_f32 %0, %1" : "=v"(r) : "v"(x));   // v_exp_f32 IS 2^x
    return r;
#endif
}

// pack two f32 -> one u32 of 2x bf16 (RNE), single instruction on gfx950
__device__ inline unsigned cvt_pk_bf16(float lo, float hi) {
    unsigned r;
    asm("v_cvt_pk_bf16_f32 %0, %1, %2" : "=v"(r) : "v"(lo), "v"(hi));
    return r;
}

__device__ inline unsigned short bfhi_u(float x) {   // truncation (Dekker hi)
    union { float f; unsigned u; } u; u.f = x;
    return (unsigned short)(u.u >> 16);
}
__device__ inline float bf2f(unsigned short h) {
    union { unsigned u; float f; } u; u.u = ((unsigned)h) << 16;
    return u.f;
}
__device__ inline unsigned short bf_rne(float x) {   // round-nearest-even bf16
    union { float f; unsigned u; } u; u.f = x;
    return (unsigned short)((u.u + 0x7FFFu + ((u.u >> 16) & 1u)) >> 16);
}

struct Smem16 {                                   // 31360 B (win16 path)
    unsigned short qpack[4][256][8];              // 16384
    unsigned short vperm[4][5][272];              // 10880 (row 544 B, 16B-aligned)
    float l_lds[4][256];                          // 4096
};
struct Smem8 {                                    // 16384 B (win8 path)
    float4 qs[8][64];
    float4 vs[8][64];
};
union SmemU { Smem16 a; Smem8 b; };

__global__ __launch_bounds__(512) void fused_attn(const float* __restrict__ x,
                                                  float* __restrict__ out) {
    __shared__ __align__(16) SmemU smem;

    const int tid  = threadIdx.x;
    const int lane = tid & 63;
    const int wave = tid >> 6;

    if (blockIdx.x < 1024) {
        // ================= branch 1: 16x16, shift (8,8), MFMA ================
        const int blk = blockIdx.x;
        const int wj = blk & 15, wi = (blk >> 4) & 15, b = blk >> 8;
        const int head = wave >> 1;
        const int half = wave & 1;
        const int g = lane >> 4;
        const int n = lane & 15;

        // ---- global -> LDS; q * ALPHA then Dekker split; v bf16-RNE permuted.
#pragma unroll
        for (int k = 0; k < 16; ++k) {
            const int f = k * 512 + tid;
            const int c = f >> 8;            // 0..31
            const int t = f & 255;
            const int gi = (wi * 16 + (t >> 4) + 248) & 255;   // src = rolled-8 mod 256
            const int gj = (wj * 16 + (t & 15) + 248) & 255;
            float val = x[((size_t)b * CIN + 32 + c) * PLANE + (size_t)gi * Ww + gj];
            const int h = (c >> 2) & 3, ch = c & 3;
            if (c < 16) {
                val *= ALPHA;
                const unsigned short hi = bfhi_u(val);
                smem.a.qpack[h][t][ch]     = hi;
                smem.a.qpack[h][t][4 + ch] = bfhi_u(val - bf2f(hi));
            } else {
                // source s-offset rr = hi*16 + 4g + j  ->  pos = g*8 + hi*4 + j
                const int rr = t & 31;
                const int pos = (t & ~31) + ((rr >> 2) & 3) * 8 + (rr >> 4) * 4 + (rr & 3);
                smem.a.vperm[h][ch][pos] = bf_rne(val);
            }
        }
        // ones channel-row: read as K-slot data -> row sums l
#pragma unroll
        for (int k = 0; k < 2; ++k) {
            const int i = k * 512 + tid;
            smem.a.vperm[i >> 8][4][i & 255] = (unsigned short)0x3F80;
        }
        __syncthreads();

        const int tbase = half * 128;

        const unsigned long long m0  = (g == 0) ? ~0ull : 0ull;
        const unsigned long long m1  = (g == 1) ? ~0ull : 0ull;
        const unsigned long long m01 = (g <  2) ? ~0ull : 0ull;

        // QK K-slot placement: A:[s_hi(g0) s_hi(g1) 0 0 | s_lo(g0) 0 0 0]
        //                      B:[t_hi(g0) t_lo(g1) 0 0 | t_hi(g0) 0 0 0]
        short8 BQ[8];
#pragma unroll
        for (int m = 0; m < 8; ++m) {
            union { short8 v; unsigned long long q[2]; } u, f;
            u.v = *(const short8*)&smem.a.qpack[head][tbase + m * 16 + n][0];
            f.q[0] = (u.q[0] & m0) | (u.q[1] & m1);
            f.q[1] = u.q[0] & m0;
            BQ[m] = f.v;
        }

        f32x4 O[8];
#pragma unroll
        for (int m = 0; m < 8; ++m) O[m] = (f32x4){0.f, 0.f, 0.f, 0.f};
        const f32x4 zero4 = (f32x4){0.f, 0.f, 0.f, 0.f};

        for (int c = 0; c < 8; ++c) {                 // s-chunks of 32
            short8 AQ[2];
#pragma unroll
            for (int a = 0; a < 2; ++a) {
                union { short8 v; unsigned long long q[2]; } u, f;
                u.v = *(const short8*)&smem.a.qpack[head][c * 32 + a * 16 + n][0];
                f.q[0] = u.q[0] & m01;
                f.q[1] = u.q[1] & m0;
                AQ[a] = f.v;
            }

            // V B-fragment: pre-permuted -> one 16B read (rows 0..3 data, 4 ones)
            short8 Vhf = {0, 0, 0, 0, 0, 0, 0, 0};
            if (n < 5) Vhf = *(const short8*)&smem.a.vperm[head][n][c * 32 + g * 8];

            // per m: QK (2 MFMA) -> exp2 -> cvt_pk -> PV (1 MFMA).
            // Symmetry: C[a][m] lane (g,n) reg r = P[m*16+n][c*32 + a*16 + 4g+r].
#pragma unroll
            for (int m = 0; m < 8; ++m) {
                const f32x4 c0 = __builtin_amdgcn_mfma_f32_16x16x32_bf16(AQ[0], BQ[m], zero4, 0, 0, 0);
                const f32x4 c1 = __builtin_amdgcn_mfma_f32_16x16x32_bf16(AQ[1], BQ[m], zero4, 0, 0, 0);
                union { unsigned u[4]; short8 s; } pk;
                pk.u[0] = cvt_pk_bf16(fexp2(c0[0]), fexp2(c0[1]));
                pk.u[1] = cvt_pk_bf16(fexp2(c0[2]), fexp2(c0[3]));
                pk.u[2] = cvt_pk_bf16(fexp2(c1[0]), fexp2(c1[1]));
                pk.u[3] = cvt_pk_bf16(fexp2(c1[2]), fexp2(c1[3]));
                O[m] = __builtin_amdgcn_mfma_f32_16x16x32_bf16(pk.s, Vhf, O[m], 0, 0, 0);
            }
        }

        // ---- normalize: O column 4 = l[token]; publish 1/l via LDS
        // (wave-local; DS ops are wave-ordered, writer/reader in same wave).
        if (n == 4) {
#pragma unroll
            for (int m = 0; m < 8; ++m)
#pragma unroll
                for (int r = 0; r < 4; ++r)
                    smem.a.l_lds[head][tbase + m * 16 + 4 * g + r] = __builtin_amdgcn_rcpf(O[m][r]);
        }
        if (n < 4) {
            float* op = out + ((size_t)b * COUT + 16 + head * 4 + n) * PLANE;
#pragma unroll
            for (int m = 0; m < 8; ++m) {
                const f32x4 inv4 = *(const f32x4*)&smem.a.l_lds[head][tbase + m * 16 + 4 * g];
                const int gi  = (wi * 16 + half * 8 + m + 248) & 255;
                const int gj0 = (wj * 16 + 4 * g + 248) & 255; // mult of 4: no wrap in float4
                f32x4 res;
                res[0] = O[m][0] * inv4[0];
                res[1] = O[m][1] * inv4[1];
                res[2] = O[m][2] * inv4[2];
                res[3] = O[m][3] * inv4[3];
                *(f32x4*)(op + (size_t)gi * Ww + gj0) = res;
            }
        }
    } else {
        // ============ branch 0: 8x8, no shift, fp32 vector (per-wave) ========
        int bid = (blockIdx.x - 1024) * 8 + wave;   // 0..16383
        const int wj   = bid & 31; bid >>= 5;
        const int wi   = bid & 31; bid >>= 5;
        const int head = bid & 3;  bid >>= 2;
        const int b    = bid;

        const int t  = lane;
        const int gi = wi * 8 + (t >> 3);
        const int gj = wj * 8 + (t & 7);
        const size_t pix = (size_t)gi * Ww + gj;

        const float* xq = x + (size_t)b * CIN * PLANE + (size_t)(head * 4) * PLANE + pix;
        const float* xv = xq + 16 * PLANE;

        float4* qs = smem.b.qs[wave];
        float4* vs = smem.b.vs[wave];

        float4 q, v;
        q.x = xq[0] * ALPHA; q.y = xq[PLANE] * ALPHA;
        q.z = xq[2 * PLANE] * ALPHA; q.w = xq[3 * PLANE] * ALPHA;
        v.x = xv[0];         v.y = xv[PLANE];     v.z = xv[2 * PLANE]; v.w = xv[3 * PLANE];
        qs[t] = q;
        vs[t] = v;
        // no barrier: qs/vs slices are wave-private; DS pipe is in-order per wave.

        float l = 0.f;
        float4 acc = make_float4(0.f, 0.f, 0.f, 0.f);
#pragma unroll
        for (int s = 0; s < 64; ++s) {
            const float4 p = qs[s];
            const float d = q.x * p.x + q.y * p.y + q.z * p.z + q.w * p.w;
            const float e = fexp2(d);
            l += e;
            const float4 vv = vs[s];
            acc.x += e * vv.x; acc.y += e * vv.y;
            acc.z += e * vv.z; acc.w += e * vv.w;
        }
        const float inv = 1.0f / l;

        float* ob = out + (size_t)b * COUT * PLANE + (size_t)(head * 4) * PLANE + pix;
        ob[0]         = acc.x * inv;
        ob[PLANE]     = acc.y * inv;
        ob[2 * PLANE] = acc.z * inv;
        ob[3 * PLANE] = acc.w * inv;
    }
}

extern "C" void kernel_launch(void* const* d_in, const int* in_sizes, int n_in,
                              void* d_out, int out_size, void* d_ws, size_t ws_size,
                              hipStream_t stream) {
    const float* x = (const float*)d_in[0];
    float* out = (float*)d_out;

    // blocks 0..1023: win16 (long pole, dispatched first);
    // blocks 1024..3071: win8 (16384 window-heads / 8 waves per block).
    hipLaunchKernelGGL(fused_attn, dim3(3072), dim3(512), 0, stream, x, out);
}